// Round 7
// baseline (87.586 us; speedup 1.0000x reference)
//
#include <hip/hip_runtime.h>

// TripletLoss, N=384, D=512, fp32 in, int labels, fp32 scalar out.
// loss = sum_a sum_p sum_n relu(d(a,p)-d(a,n)+1) / num_valid (diag counts as pos)
//
// R6 post-mortem: total 75us = ~40us harness ws-poison fill (fixed floor) +
// ~11us kernels + 3-dispatch gaps. R7: K-split-2 distance kernel (1152 waves,
// was 576 on 1024 SIMDs; ~2x faster), 32x16 tiles kill Bs 4-way bank conflict,
// fold final reduce into K2 via zero-inited ticket -> 2 dispatches.

#define NPTS 384
#define DIM  512
#define TSI  32          // i-tile
#define TSJ  16          // j-tile
#define BK   64
#define PITCH 68         // floats; 272B = 17*16B keeps float4 LDS alignment
#define NT1  128
#define NT2  384
#define KSPLIT 2

// ---------------- K1: d^2 partials, K split in two halves -------------------
__global__ __launch_bounds__(NT1) void dist_tile(
    const float* __restrict__ X,
    float* __restrict__ D0, float* __restrict__ D1,
    float* __restrict__ ws_sum, unsigned long long* __restrict__ ws_cnt,
    unsigned* __restrict__ ws_ticket)
{
    __shared__ float As[TSI * PITCH];    // 8704 B
    __shared__ float Bs[TSJ * PITCH];    // 4352 B
    const int t  = threadIdx.x;
    const int tx = t & 7, ty = t >> 3;   // 8x16 thread grid, 2x2 per thread
    const int bj = blockIdx.x * TSJ;
    const int bi = blockIdx.y * TSI;
    const int kz = blockIdx.z;

    if (blockIdx.x == 0 && blockIdx.y == 0 && kz == 0 && t == 0) {
        *ws_sum = 0.0f; *ws_cnt = 0ull; *ws_ticket = 0u;   // ws is poisoned 0xAA
    }

    const float4* X4 = (const float4*)X;           // row pitch DIM/4 = 128
    const int r = t >> 4, c4 = t & 15;             // staging: 8 rows x 16 f4
    const int kb4 = kz * (DIM / KSPLIT / 4);       // 64 float4 per half

    float4 pa0, pa1, pa2, pa3, pb0, pb1;
    {   // stage k-tile 0 of this half
        const int k4 = kb4 + c4;
        pa0 = X4[(size_t)(bi + r)      * 128 + k4];
        pa1 = X4[(size_t)(bi + r + 8)  * 128 + k4];
        pa2 = X4[(size_t)(bi + r + 16) * 128 + k4];
        pa3 = X4[(size_t)(bi + r + 24) * 128 + k4];
        pb0 = X4[(size_t)(bj + r)      * 128 + k4];
        pb1 = X4[(size_t)(bj + r + 8)  * 128 + k4];
        *(float4*)&As[(r)      * PITCH + c4 * 4] = pa0;
        *(float4*)&As[(r + 8)  * PITCH + c4 * 4] = pa1;
        *(float4*)&As[(r + 16) * PITCH + c4 * 4] = pa2;
        *(float4*)&As[(r + 24) * PITCH + c4 * 4] = pa3;
        *(float4*)&Bs[(r)      * PITCH + c4 * 4] = pb0;
        *(float4*)&Bs[(r + 8)  * PITCH + c4 * 4] = pb1;
    }
    __syncthreads();

    float acc00 = 0.f, acc01 = 0.f, acc10 = 0.f, acc11 = 0.f;
    const int NKT = DIM / KSPLIT / BK;             // 4 k-tiles per half

    for (int kt = 0; kt < NKT; ++kt) {
        if (kt < NKT - 1) {                        // register prefetch next tile
            const int k4 = kb4 + (kt + 1) * (BK / 4) + c4;
            pa0 = X4[(size_t)(bi + r)      * 128 + k4];
            pa1 = X4[(size_t)(bi + r + 8)  * 128 + k4];
            pa2 = X4[(size_t)(bi + r + 16) * 128 + k4];
            pa3 = X4[(size_t)(bi + r + 24) * 128 + k4];
            pb0 = X4[(size_t)(bj + r)      * 128 + k4];
            pb1 = X4[(size_t)(bj + r + 8)  * 128 + k4];
        }
#pragma unroll
        for (int kk = 0; kk < BK / 4; ++kk) {
            const float4 a0 = *(const float4*)&As[(2 * ty)     * PITCH + kk * 4];
            const float4 a1 = *(const float4*)&As[(2 * ty + 1) * PITCH + kk * 4];
            const float4 b0 = *(const float4*)&Bs[(2 * tx)     * PITCH + kk * 4];
            const float4 b1 = *(const float4*)&Bs[(2 * tx + 1) * PITCH + kk * 4];
            float d;
            d = a0.x - b0.x; acc00 = fmaf(d, d, acc00);
            d = a0.y - b0.y; acc00 = fmaf(d, d, acc00);
            d = a0.z - b0.z; acc00 = fmaf(d, d, acc00);
            d = a0.w - b0.w; acc00 = fmaf(d, d, acc00);
            d = a0.x - b1.x; acc01 = fmaf(d, d, acc01);
            d = a0.y - b1.y; acc01 = fmaf(d, d, acc01);
            d = a0.z - b1.z; acc01 = fmaf(d, d, acc01);
            d = a0.w - b1.w; acc01 = fmaf(d, d, acc01);
            d = a1.x - b0.x; acc10 = fmaf(d, d, acc10);
            d = a1.y - b0.y; acc10 = fmaf(d, d, acc10);
            d = a1.z - b0.z; acc10 = fmaf(d, d, acc10);
            d = a1.w - b0.w; acc10 = fmaf(d, d, acc10);
            d = a1.x - b1.x; acc11 = fmaf(d, d, acc11);
            d = a1.y - b1.y; acc11 = fmaf(d, d, acc11);
            d = a1.z - b1.z; acc11 = fmaf(d, d, acc11);
            d = a1.w - b1.w; acc11 = fmaf(d, d, acc11);
        }
        __syncthreads();
        if (kt < NKT - 1) {
            *(float4*)&As[(r)      * PITCH + c4 * 4] = pa0;
            *(float4*)&As[(r + 8)  * PITCH + c4 * 4] = pa1;
            *(float4*)&As[(r + 16) * PITCH + c4 * 4] = pa2;
            *(float4*)&As[(r + 24) * PITCH + c4 * 4] = pa3;
            *(float4*)&Bs[(r)      * PITCH + c4 * 4] = pb0;
            *(float4*)&Bs[(r + 8)  * PITCH + c4 * 4] = pb1;
            __syncthreads();
        }
    }

    // diagonal elements: As/Bs hold identical copies of the same X rows -> 0
    float* __restrict__ Dout = kz ? D1 : D0;
    const int gi = bi + 2 * ty, gj = bj + 2 * tx;
    *(float2*)&Dout[(size_t)gi       * NPTS + gj] = make_float2(acc00, acc01);
    *(float2*)&Dout[(size_t)(gi + 1) * NPTS + gj] = make_float2(acc10, acc11);
}

// ---------------- K2: per-anchor pair sum + ticket finalize -----------------
__global__ __launch_bounds__(NT2) void pair_final(
    const float* __restrict__ D0, const float* __restrict__ D1,
    const int* __restrict__ labels,
    float* __restrict__ ws_sum, unsigned long long* __restrict__ ws_cnt,
    unsigned* __restrict__ ws_ticket, float* __restrict__ out)
{
    __shared__ float s_dp[NPTS];
    __shared__ float s_dn[NPTS];
    __shared__ int   s_cp[NT2 / 64], s_cn[NT2 / 64];
    __shared__ float s_wred[NT2 / 64];

    const int t = threadIdx.x, lane = t & 63, w = t >> 6;
    const int a = blockIdx.x;
    const int lab_a = labels[a];

    const float dv  = sqrtf(D0[(size_t)a * NPTS + t] + D1[(size_t)a * NPTS + t]);
    const bool  isp = (labels[t] == lab_a);

    const unsigned long long m = __ballot(isp);
    if (lane == 0) { s_cp[w] = __popcll(m); s_cn[w] = 64 - __popcll(m); }
    __syncthreads();

    int basep = 0, basen = 0, np = 0, nn = 0;
#pragma unroll
    for (int i = 0; i < NT2 / 64; ++i) {
        if (i < w) { basep += s_cp[i]; basen += s_cn[i]; }
        np += s_cp[i]; nn += s_cn[i];
    }
    const unsigned long long blw = (1ull << lane) - 1ull;
    if (isp) s_dp[basep + __popcll(m  & blw)] = dv;
    else     s_dn[basen + __popcll(~m & blw)] = dv;
    __syncthreads();

    float local = 0.f;
    for (int p = 0; p < np; ++p) {
        const float c = s_dp[p] + 1.0f;          // MARGIN
        for (int n = t; n < nn; n += NT2) {
            const float v = c - s_dn[n];
            local += (v > 0.f) ? v : 0.f;
        }
    }
    for (int off = 32; off; off >>= 1) local += __shfl_down(local, off, 64);
    if (lane == 0) s_wred[w] = local;
    __syncthreads();

    if (t == 0) {
        float bs = 0.f;
        for (int i = 0; i < NT2 / 64; ++i) bs += s_wred[i];
        atomicAdd(ws_sum, bs);                                   // device scope
        atomicAdd(ws_cnt, (unsigned long long)(np * nn));
        __threadfence();
        const unsigned tk = atomicAdd(ws_ticket, 1u);
        if (tk == (unsigned)gridDim.x - 1u) {                    // last block
            const float ts = atomicAdd(ws_sum, 0.0f);            // coherent read
            const unsigned long long tc = atomicAdd(ws_cnt, 0ull);
            *out = (float)((double)ts / ((double)tc + 1e-16));
        }
    }
}

extern "C" void kernel_launch(void* const* d_in, const int* in_sizes, int n_in,
                              void* d_out, int out_size, void* d_ws, size_t ws_size,
                              hipStream_t stream) {
    (void)in_sizes; (void)n_in; (void)out_size; (void)ws_size;
    const float* X = (const float*)d_in[0];
    const int* labels = (const int*)d_in[1];

    const size_t dsz = (size_t)NPTS * NPTS * sizeof(float);      // 589824 B
    float* D0 = (float*)d_ws;
    float* D1 = (float*)((char*)d_ws + dsz);
    float* ws_sum = (float*)((char*)d_ws + 2 * dsz);
    unsigned long long* ws_cnt = (unsigned long long*)((char*)d_ws + 2 * dsz + 8);
    unsigned* ws_ticket = (unsigned*)((char*)d_ws + 2 * dsz + 16);

    dist_tile <<<dim3(NPTS / TSJ, NPTS / TSI, KSPLIT), dim3(NT1), 0, stream>>>(
        X, D0, D1, ws_sum, ws_cnt, ws_ticket);
    pair_final<<<dim3(NPTS), dim3(NT2), 0, stream>>>(
        D0, D1, labels, ws_sum, ws_cnt, ws_ticket, (float*)d_out);
}

// Round 9
// 83.835 us; speedup vs baseline: 1.0447x; 1.0447x over previous
//
#include <hip/hip_runtime.h>

// TripletLoss, N=384, D=512, fp32 in, int labels, fp32 scalar out.
// loss = sum_a sum_p sum_n relu(d(a,p)-d(a,n)+1) / num_valid (diag counts as pos)
//
// R8 post-mortem: hipLaunchCooperativeKernel never executed under graph
// capture (out stayed 0). R9: back to plain launches, TWO nodes, fence-free:
// K1 = R7's proven split-K2 tiled d^2 (+ zeroes out), K2 = 96 blocks x 4
// anchors, per-block num_valid from label histogram, ONE fp32 atomicAdd(out)
// per block. No ticket, no __threadfence (R7's +12us lesson).

#define NPTS 384
#define DIM  512
#define TSI  32
#define TSJ  16
#define BK   64
#define PITCH 68         // floats; 272B row pitch keeps float4 LDS alignment
#define NT1  128
#define NT2  384
#define KSPLIT 2
#define APB  4           // anchors per block in K2
#define NBLK2 (NPTS / APB)   // 96

// ---------------- K1: d^2 partials, K split in two halves -------------------
__global__ __launch_bounds__(NT1) void dist_tile(
    const float* __restrict__ X,
    float* __restrict__ D0, float* __restrict__ D1,
    float* __restrict__ out)
{
    __shared__ float As[TSI * PITCH];    // 8704 B
    __shared__ float Bs[TSJ * PITCH];    // 4352 B
    const int t  = threadIdx.x;
    const int tx = t & 7, ty = t >> 3;   // 8x16 thread grid, 2x2 per thread
    const int bj = blockIdx.x * TSJ;
    const int bi = blockIdx.y * TSI;
    const int kz = blockIdx.z;

    if (blockIdx.x == 0 && blockIdx.y == 0 && kz == 0 && t == 0)
        *out = 0.0f;                     // K2 (next dispatch) accumulates here

    const float4* X4 = (const float4*)X;           // row pitch DIM/4 = 128
    const int r = t >> 4, c4 = t & 15;             // staging: 8 rows x 16 f4
    const int kb4 = kz * (DIM / KSPLIT / 4);       // 64 float4 per half

    float4 pa0, pa1, pa2, pa3, pb0, pb1;
    {   // stage k-tile 0 of this half
        const int k4 = kb4 + c4;
        pa0 = X4[(size_t)(bi + r)      * 128 + k4];
        pa1 = X4[(size_t)(bi + r + 8)  * 128 + k4];
        pa2 = X4[(size_t)(bi + r + 16) * 128 + k4];
        pa3 = X4[(size_t)(bi + r + 24) * 128 + k4];
        pb0 = X4[(size_t)(bj + r)      * 128 + k4];
        pb1 = X4[(size_t)(bj + r + 8)  * 128 + k4];
        *(float4*)&As[(r)      * PITCH + c4 * 4] = pa0;
        *(float4*)&As[(r + 8)  * PITCH + c4 * 4] = pa1;
        *(float4*)&As[(r + 16) * PITCH + c4 * 4] = pa2;
        *(float4*)&As[(r + 24) * PITCH + c4 * 4] = pa3;
        *(float4*)&Bs[(r)      * PITCH + c4 * 4] = pb0;
        *(float4*)&Bs[(r + 8)  * PITCH + c4 * 4] = pb1;
    }
    __syncthreads();

    float acc00 = 0.f, acc01 = 0.f, acc10 = 0.f, acc11 = 0.f;
    const int NKT = DIM / KSPLIT / BK;             // 4 k-tiles per half

    for (int kt = 0; kt < NKT; ++kt) {
        if (kt < NKT - 1) {                        // register prefetch next tile
            const int k4 = kb4 + (kt + 1) * (BK / 4) + c4;
            pa0 = X4[(size_t)(bi + r)      * 128 + k4];
            pa1 = X4[(size_t)(bi + r + 8)  * 128 + k4];
            pa2 = X4[(size_t)(bi + r + 16) * 128 + k4];
            pa3 = X4[(size_t)(bi + r + 24) * 128 + k4];
            pb0 = X4[(size_t)(bj + r)      * 128 + k4];
            pb1 = X4[(size_t)(bj + r + 8)  * 128 + k4];
        }
#pragma unroll
        for (int kk = 0; kk < BK / 4; ++kk) {
            const float4 a0 = *(const float4*)&As[(2 * ty)     * PITCH + kk * 4];
            const float4 a1 = *(const float4*)&As[(2 * ty + 1) * PITCH + kk * 4];
            const float4 b0 = *(const float4*)&Bs[(2 * tx)     * PITCH + kk * 4];
            const float4 b1 = *(const float4*)&Bs[(2 * tx + 1) * PITCH + kk * 4];
            float d;
            d = a0.x - b0.x; acc00 = fmaf(d, d, acc00);
            d = a0.y - b0.y; acc00 = fmaf(d, d, acc00);
            d = a0.z - b0.z; acc00 = fmaf(d, d, acc00);
            d = a0.w - b0.w; acc00 = fmaf(d, d, acc00);
            d = a0.x - b1.x; acc01 = fmaf(d, d, acc01);
            d = a0.y - b1.y; acc01 = fmaf(d, d, acc01);
            d = a0.z - b1.z; acc01 = fmaf(d, d, acc01);
            d = a0.w - b1.w; acc01 = fmaf(d, d, acc01);
            d = a1.x - b0.x; acc10 = fmaf(d, d, acc10);
            d = a1.y - b0.y; acc10 = fmaf(d, d, acc10);
            d = a1.z - b0.z; acc10 = fmaf(d, d, acc10);
            d = a1.w - b0.w; acc10 = fmaf(d, d, acc10);
            d = a1.x - b1.x; acc11 = fmaf(d, d, acc11);
            d = a1.y - b1.y; acc11 = fmaf(d, d, acc11);
            d = a1.z - b1.z; acc11 = fmaf(d, d, acc11);
            d = a1.w - b1.w; acc11 = fmaf(d, d, acc11);
        }
        __syncthreads();
        if (kt < NKT - 1) {
            *(float4*)&As[(r)      * PITCH + c4 * 4] = pa0;
            *(float4*)&As[(r + 8)  * PITCH + c4 * 4] = pa1;
            *(float4*)&As[(r + 16) * PITCH + c4 * 4] = pa2;
            *(float4*)&As[(r + 24) * PITCH + c4 * 4] = pa3;
            *(float4*)&Bs[(r)      * PITCH + c4 * 4] = pb0;
            *(float4*)&Bs[(r + 8)  * PITCH + c4 * 4] = pb1;
            __syncthreads();
        }
    }

    // diagonal elements: As/Bs hold identical copies of the same X rows -> 0
    float* __restrict__ Dout = kz ? D1 : D0;
    const int gi = bi + 2 * ty, gj = bj + 2 * tx;
    *(float2*)&Dout[(size_t)gi       * NPTS + gj] = make_float2(acc00, acc01);
    *(float2*)&Dout[(size_t)(gi + 1) * NPTS + gj] = make_float2(acc10, acc11);
}

// -------- K2: 4 anchors/block, ballot compaction, single atomicAdd(out) -----
__global__ __launch_bounds__(NT2) void pair_final(
    const float* __restrict__ D0, const float* __restrict__ D1,
    const int* __restrict__ labels, float* __restrict__ out)
{
    __shared__ float s_dp[NPTS];
    __shared__ float s_dn[NPTS];
    __shared__ int   s_lab[NPTS];
    __shared__ int   s_hist[24];
    __shared__ int   s_cp[NT2 / 64], s_cn[NT2 / 64];
    __shared__ float s_wred[NT2 / 64];

    const int t = threadIdx.x, lane = t & 63, w = t >> 6;

    if (t < 24) s_hist[t] = 0;
    s_lab[t] = labels[t];
    __syncthreads();
    atomicAdd(&s_hist[s_lab[t]], 1);
    __syncthreads();

    // num_valid = sum_cls c^2 * (N - c)  — identical in every block
    long long nv = 0;
    for (int c = 0; c < 24; ++c) {
        const long long cc = s_hist[c];
        nv += cc * cc * (long long)(NPTS - cc);
    }

    float bsum = 0.f;                    // meaningful in t==0 only

    for (int ai = 0; ai < APB; ++ai) {
        const int a = blockIdx.x * APB + ai;
        const int lab_a = s_lab[a];

        const float dv  = sqrtf(D0[(size_t)a * NPTS + t] + D1[(size_t)a * NPTS + t]);
        const bool  isp = (s_lab[t] == lab_a);

        const unsigned long long m = __ballot(isp);
        if (lane == 0) { s_cp[w] = __popcll(m); s_cn[w] = 64 - __popcll(m); }
        __syncthreads();

        int basep = 0, basen = 0, np = 0, nn = 0;
#pragma unroll
        for (int i = 0; i < NT2 / 64; ++i) {
            if (i < w) { basep += s_cp[i]; basen += s_cn[i]; }
            np += s_cp[i]; nn += s_cn[i];
        }
        const unsigned long long blw = (1ull << lane) - 1ull;
        if (isp) s_dp[basep + __popcll(m  & blw)] = dv;
        else     s_dn[basen + __popcll(~m & blw)] = dv;
        __syncthreads();

        float local = 0.f;
        for (int p = 0; p < np; ++p) {
            const float c = s_dp[p] + 1.0f;          // MARGIN
            for (int n = t; n < nn; n += NT2) {
                const float v = c - s_dn[n];
                local += (v > 0.f) ? v : 0.f;
            }
        }
        for (int off = 32; off; off >>= 1) local += __shfl_down(local, off, 64);
        if (lane == 0) s_wred[w] = local;
        __syncthreads();
        if (t == 0)
            for (int i = 0; i < NT2 / 64; ++i) bsum += s_wred[i];
        __syncthreads();                 // s_dp/s_dn/s_cp/s_wred reused next ai
    }

    if (t == 0) {
        const float contrib = (float)((double)bsum / ((double)nv + 1e-16));
        atomicAdd(out, contrib);         // 96 staggered arrivals, device scope
    }
}

extern "C" void kernel_launch(void* const* d_in, const int* in_sizes, int n_in,
                              void* d_out, int out_size, void* d_ws, size_t ws_size,
                              hipStream_t stream) {
    (void)in_sizes; (void)n_in; (void)out_size; (void)ws_size;
    const float* X = (const float*)d_in[0];
    const int* labels = (const int*)d_in[1];

    const size_t dsz = (size_t)NPTS * NPTS * sizeof(float);      // 589824 B
    float* D0 = (float*)d_ws;
    float* D1 = (float*)((char*)d_ws + dsz);

    dist_tile <<<dim3(NPTS / TSJ, NPTS / TSI, KSPLIT), dim3(NT1), 0, stream>>>(
        X, D0, D1, (float*)d_out);
    pair_final<<<dim3(NBLK2), dim3(NT2), 0, stream>>>(
        D0, D1, labels, (float*)d_out);
}

// Round 10
// 77.956 us; speedup vs baseline: 1.1235x; 1.0754x over previous
//
#include <hip/hip_runtime.h>

// TripletLoss, N=384, D=512, fp32 in, int labels, fp32 scalar out.
// loss = sum_a sum_p sum_n relu(d(a,p)-d(a,n)+1) / num_valid (diag counts as pos)
//
// R9 post-mortem: 4-anchors/block K2 on 96 blocks serialized the pair phase
// (+4us vs R6's 384-block K2). R10: 2 nodes, K2 = 384 blocks x 1 anchor,
// per-block num_valid from label histogram, ONE atomicAdd(out) per block.
// K1 = proven split-K2 tiled d^2 (also zero-inits out via kernel boundary).
//
// Budget (stable over R6-R9): ~40us harness ws-poison fill + ~22us fixed
// harness nodes/gaps + our ~8us kernels. This round removes the last
// self-inflicted serialization; beyond it we are at the harness floor.

#define NPTS 384
#define DIM  512
#define TSI  32
#define TSJ  16
#define BK   64
#define PITCH 68         // floats; 272B row pitch keeps float4 LDS alignment
#define NT1  128
#define NT2  384
#define KSPLIT 2

// ---------------- K1: d^2 partials, K split in two halves -------------------
__global__ __launch_bounds__(NT1) void dist_tile(
    const float* __restrict__ X,
    float* __restrict__ D0, float* __restrict__ D1,
    float* __restrict__ out)
{
    __shared__ float As[TSI * PITCH];    // 8704 B
    __shared__ float Bs[TSJ * PITCH];    // 4352 B
    const int t  = threadIdx.x;
    const int tx = t & 7, ty = t >> 3;   // 8x16 thread grid, 2x2 per thread
    const int bj = blockIdx.x * TSJ;
    const int bi = blockIdx.y * TSI;
    const int kz = blockIdx.z;

    if (blockIdx.x == 0 && blockIdx.y == 0 && kz == 0 && t == 0)
        *out = 0.0f;                     // K2 (next dispatch) accumulates here

    const float4* X4 = (const float4*)X;           // row pitch DIM/4 = 128
    const int r = t >> 4, c4 = t & 15;             // staging: 8 rows x 16 f4
    const int kb4 = kz * (DIM / KSPLIT / 4);       // 64 float4 per half

    float4 pa0, pa1, pa2, pa3, pb0, pb1;
    {   // stage k-tile 0 of this half
        const int k4 = kb4 + c4;
        pa0 = X4[(size_t)(bi + r)      * 128 + k4];
        pa1 = X4[(size_t)(bi + r + 8)  * 128 + k4];
        pa2 = X4[(size_t)(bi + r + 16) * 128 + k4];
        pa3 = X4[(size_t)(bi + r + 24) * 128 + k4];
        pb0 = X4[(size_t)(bj + r)      * 128 + k4];
        pb1 = X4[(size_t)(bj + r + 8)  * 128 + k4];
        *(float4*)&As[(r)      * PITCH + c4 * 4] = pa0;
        *(float4*)&As[(r + 8)  * PITCH + c4 * 4] = pa1;
        *(float4*)&As[(r + 16) * PITCH + c4 * 4] = pa2;
        *(float4*)&As[(r + 24) * PITCH + c4 * 4] = pa3;
        *(float4*)&Bs[(r)      * PITCH + c4 * 4] = pb0;
        *(float4*)&Bs[(r + 8)  * PITCH + c4 * 4] = pb1;
    }
    __syncthreads();

    float acc00 = 0.f, acc01 = 0.f, acc10 = 0.f, acc11 = 0.f;
    const int NKT = DIM / KSPLIT / BK;             // 4 k-tiles per half

    for (int kt = 0; kt < NKT; ++kt) {
        if (kt < NKT - 1) {                        // register prefetch next tile
            const int k4 = kb4 + (kt + 1) * (BK / 4) + c4;
            pa0 = X4[(size_t)(bi + r)      * 128 + k4];
            pa1 = X4[(size_t)(bi + r + 8)  * 128 + k4];
            pa2 = X4[(size_t)(bi + r + 16) * 128 + k4];
            pa3 = X4[(size_t)(bi + r + 24) * 128 + k4];
            pb0 = X4[(size_t)(bj + r)      * 128 + k4];
            pb1 = X4[(size_t)(bj + r + 8)  * 128 + k4];
        }
#pragma unroll
        for (int kk = 0; kk < BK / 4; ++kk) {
            const float4 a0 = *(const float4*)&As[(2 * ty)     * PITCH + kk * 4];
            const float4 a1 = *(const float4*)&As[(2 * ty + 1) * PITCH + kk * 4];
            const float4 b0 = *(const float4*)&Bs[(2 * tx)     * PITCH + kk * 4];
            const float4 b1 = *(const float4*)&Bs[(2 * tx + 1) * PITCH + kk * 4];
            float d;
            d = a0.x - b0.x; acc00 = fmaf(d, d, acc00);
            d = a0.y - b0.y; acc00 = fmaf(d, d, acc00);
            d = a0.z - b0.z; acc00 = fmaf(d, d, acc00);
            d = a0.w - b0.w; acc00 = fmaf(d, d, acc00);
            d = a0.x - b1.x; acc01 = fmaf(d, d, acc01);
            d = a0.y - b1.y; acc01 = fmaf(d, d, acc01);
            d = a0.z - b1.z; acc01 = fmaf(d, d, acc01);
            d = a0.w - b1.w; acc01 = fmaf(d, d, acc01);
            d = a1.x - b0.x; acc10 = fmaf(d, d, acc10);
            d = a1.y - b0.y; acc10 = fmaf(d, d, acc10);
            d = a1.z - b0.z; acc10 = fmaf(d, d, acc10);
            d = a1.w - b0.w; acc10 = fmaf(d, d, acc10);
            d = a1.x - b1.x; acc11 = fmaf(d, d, acc11);
            d = a1.y - b1.y; acc11 = fmaf(d, d, acc11);
            d = a1.z - b1.z; acc11 = fmaf(d, d, acc11);
            d = a1.w - b1.w; acc11 = fmaf(d, d, acc11);
        }
        __syncthreads();
        if (kt < NKT - 1) {
            *(float4*)&As[(r)      * PITCH + c4 * 4] = pa0;
            *(float4*)&As[(r + 8)  * PITCH + c4 * 4] = pa1;
            *(float4*)&As[(r + 16) * PITCH + c4 * 4] = pa2;
            *(float4*)&As[(r + 24) * PITCH + c4 * 4] = pa3;
            *(float4*)&Bs[(r)      * PITCH + c4 * 4] = pb0;
            *(float4*)&Bs[(r + 8)  * PITCH + c4 * 4] = pb1;
            __syncthreads();
        }
    }

    // diagonal elements: As/Bs hold identical copies of the same X rows -> 0
    float* __restrict__ Dout = kz ? D1 : D0;
    const int gi = bi + 2 * ty, gj = bj + 2 * tx;
    *(float2*)&Dout[(size_t)gi       * NPTS + gj] = make_float2(acc00, acc01);
    *(float2*)&Dout[(size_t)(gi + 1) * NPTS + gj] = make_float2(acc10, acc11);
}

// -------- K2: 1 anchor/block, ballot compaction, single atomicAdd(out) ------
__global__ __launch_bounds__(NT2) void pair_final(
    const float* __restrict__ D0, const float* __restrict__ D1,
    const int* __restrict__ labels, float* __restrict__ out)
{
    __shared__ float s_dp[NPTS];
    __shared__ float s_dn[NPTS];
    __shared__ int   s_lab[NPTS];
    __shared__ int   s_hist[24];
    __shared__ int   s_cp[NT2 / 64], s_cn[NT2 / 64];
    __shared__ float s_wred[NT2 / 64];

    const int t = threadIdx.x, lane = t & 63, w = t >> 6;
    const int a = blockIdx.x;

    if (t < 24) s_hist[t] = 0;
    s_lab[t] = labels[t];
    __syncthreads();
    atomicAdd(&s_hist[s_lab[t]], 1);

    const float dv  = sqrtf(D0[(size_t)a * NPTS + t] + D1[(size_t)a * NPTS + t]);
    __syncthreads();

    // num_valid = sum_cls c^2 * (N - c)  — identical in every block
    long long nv = 0;
#pragma unroll
    for (int c = 0; c < 24; ++c) {
        const long long cc = s_hist[c];
        nv += cc * cc * (long long)(NPTS - cc);
    }

    const bool isp = (s_lab[t] == s_lab[a]);
    const unsigned long long m = __ballot(isp);
    if (lane == 0) { s_cp[w] = __popcll(m); s_cn[w] = 64 - __popcll(m); }
    __syncthreads();

    int basep = 0, basen = 0, np = 0, nn = 0;
#pragma unroll
    for (int i = 0; i < NT2 / 64; ++i) {
        if (i < w) { basep += s_cp[i]; basen += s_cn[i]; }
        np += s_cp[i]; nn += s_cn[i];
    }
    const unsigned long long blw = (1ull << lane) - 1ull;
    if (isp) s_dp[basep + __popcll(m  & blw)] = dv;
    else     s_dn[basen + __popcll(~m & blw)] = dv;
    __syncthreads();

    float local = 0.f;
    for (int p = 0; p < np; ++p) {
        const float c = s_dp[p] + 1.0f;          // MARGIN
        for (int n = t; n < nn; n += NT2) {
            const float v = c - s_dn[n];
            local += (v > 0.f) ? v : 0.f;
        }
    }
    for (int off = 32; off; off >>= 1) local += __shfl_down(local, off, 64);
    if (lane == 0) s_wred[w] = local;
    __syncthreads();

    if (t == 0) {
        float bs = 0.f;
#pragma unroll
        for (int i = 0; i < NT2 / 64; ++i) bs += s_wred[i];
        // one device-scope atomic per block; arrivals staggered by completion
        atomicAdd(out, (float)((double)bs / ((double)nv + 1e-16)));
    }
}

extern "C" void kernel_launch(void* const* d_in, const int* in_sizes, int n_in,
                              void* d_out, int out_size, void* d_ws, size_t ws_size,
                              hipStream_t stream) {
    (void)in_sizes; (void)n_in; (void)out_size; (void)ws_size;
    const float* X = (const float*)d_in[0];
    const int* labels = (const int*)d_in[1];

    const size_t dsz = (size_t)NPTS * NPTS * sizeof(float);      // 589824 B
    float* D0 = (float*)d_ws;
    float* D1 = (float*)((char*)d_ws + dsz);

    dist_tile <<<dim3(NPTS / TSJ, NPTS / TSI, KSPLIT), dim3(NT1), 0, stream>>>(
        X, D0, D1, (float*)d_out);
    pair_final<<<dim3(NPTS), dim3(NT2), 0, stream>>>(
        D0, D1, labels, (float*)d_out);
}